// Round 14
// baseline (879.568 us; speedup 1.0000x reference)
//
#include <hip/hip_runtime.h>

// Problem dims (fixed)
constexpr int T  = 512;
constexpr int NB = 64;    // batch
constexpr int NI = 128;   // input
constexpr int NH = 512;   // hidden
constexpr int NO = 64;    // output

constexpr float ALPHA = 0.2f;
constexpr float NSC   = 0.063245553203367586f; // 0.1*sqrt(2*ALPHA)

typedef _Float16 h2_t __attribute__((ext_vector_type(2)));

#if defined(__has_builtin)
#  if __has_builtin(__builtin_amdgcn_fdot2)
#    define HAS_FDOT2 1
#  endif
#endif
#ifndef HAS_FDOT2
#  define HAS_FDOT2 0
#endif

// acc += dot(two f16 pairs)  — v_dot2_f32_f16 when available
__device__ __forceinline__ float dot2(uint32_t wbits, uint32_t hbits, float acc) {
#if HAS_FDOT2
    return __builtin_amdgcn_fdot2(__builtin_bit_cast(h2_t, wbits),
                                  __builtin_bit_cast(h2_t, hbits), acc, false);
#else
    const h2_t wv = __builtin_bit_cast(h2_t, wbits);
    const h2_t hv = __builtin_bit_cast(h2_t, hbits);
    return acc + (float)wv.x * (float)hv.x + (float)wv.y * (float)hv.y;
#endif
}

__device__ __forceinline__ uint32_t pk2(float x, float y) {
    return __builtin_bit_cast(uint32_t, (h2_t){(_Float16)x, (_Float16)y});
}

// ---------------------------------------------------------------------------
// Generic fp32 GEMM: C[M,N] = A[M,K] @ B[N,K]^T + bias[N]   (R3-proven)
__global__ __launch_bounds__(256) void k_gemm_nt_bias(
    const float* __restrict__ A, const float* __restrict__ Bm,
    const float* __restrict__ bias, float* __restrict__ C,
    int M, int N, int K)
{
    __shared__ __align__(16) float As[32][68];
    __shared__ __align__(16) float Bs[32][68];
    const int tid = threadIdx.x;
    const int tx = tid & 15, ty = tid >> 4;
    const long row0 = (long)blockIdx.x * 64;
    const long col0 = (long)blockIdx.y * 64;
    const int lr = tid >> 3;
    const int lq = tid & 7;

    float acc[4][4] = {};

    for (int kt = 0; kt < K; kt += 32) {
        #pragma unroll
        for (int hh = 0; hh < 2; ++hh) {
            const int r = lr + hh * 32;
            const float4 va = *(const float4*)&A[(size_t)(row0 + r) * K + kt + lq * 4];
            As[lq*4+0][r] = va.x; As[lq*4+1][r] = va.y;
            As[lq*4+2][r] = va.z; As[lq*4+3][r] = va.w;
            const float4 vb = *(const float4*)&Bm[(size_t)(col0 + r) * K + kt + lq * 4];
            Bs[lq*4+0][r] = vb.x; Bs[lq*4+1][r] = vb.y;
            Bs[lq*4+2][r] = vb.z; Bs[lq*4+3][r] = vb.w;
        }
        __syncthreads();
        #pragma unroll
        for (int kk = 0; kk < 32; ++kk) {
            const float4 a4 = *(const float4*)&As[kk][ty * 4];
            const float4 b4 = *(const float4*)&Bs[kk][tx * 4];
            const float a[4] = {a4.x, a4.y, a4.z, a4.w};
            const float b[4] = {b4.x, b4.y, b4.z, b4.w};
            #pragma unroll
            for (int i = 0; i < 4; ++i)
                #pragma unroll
                for (int j = 0; j < 4; ++j)
                    acc[i][j] += a[i] * b[j];
        }
        __syncthreads();
    }

    #pragma unroll
    for (int i = 0; i < 4; ++i) {
        const long r = row0 + ty * 4 + i;
        const int  cc = (int)col0 + tx * 4;
        float4 ov;
        ov.x = acc[i][0] + bias[cc + 0];
        ov.y = acc[i][1] + bias[cc + 1];
        ov.z = acc[i][2] + bias[cc + 2];
        ov.w = acc[i][3] + bias[cc + 3];
        *(float4*)&C[(size_t)r * N + cc] = ov;
    }
}

// ---------------------------------------------------------------------------
// u32 exchange word: [31:16]=f16(h), [15:0]=tag.  R3-proven RMW protocol.
__device__ __forceinline__ uint32_t pack_h(float h, uint32_t tag) {
    const _Float16 hf = (_Float16)h;                    // RNE f32->f16
    const uint32_t hb = __builtin_bit_cast(unsigned short, hf);
    return (hb << 16) | (tag & 0xFFFFu);
}

// ---------------------------------------------------------------------------
// Recurrent kernel = R12 structure with W in SWIZZLED f16 LDS (the R13 fix,
// resubmitted byte-identical after an infra container death — R6/R7
// precedent: identical kernel, flake confirmed by clean rerun).
//  Five rounds (R7-R12) proved the register allocator will not keep 64
//  long-lived W words in VGPRs across this barrier/atomic loop (VGPR_Count
//  48-108, scratch stream ~33MB/step = ~0.9us = the bottleneck). LDS cannot
//  be spilled: W slice (128 cols x 512 k, f16) = 128 KB of dynamic LDS.
//  Swizzle: chunk for (col, j16) stored at byte col*1024 + w*128 +
//  ((j*16) ^ ((col&7)<<4)) — each 8-lane group tiles a full 128B bank
//  window -> even bank distribution (G4/T2 pattern). Reads use the exact
//  writer addressing, so swizzle correctness is self-consistent.
// Dynamic LDS: 128K (W) + 1K (hbf) + 4K (pr) = 136192 B. 1 WG/CU.
// Everything else byte-identical to R12 (passed, absmax 0.0156):
//  64 groups (1 batch) x 4 members; member m owns cols [128m,128m+128);
//  wave w owns k-chunk [64w,64w+64); lane l -> cols {l, l+64}; h f16 in
//  LDS (8 wave-uniform b128 reads/thread); fdot2 dot; u32 RMW tagged sync,
//  2-slot parity, budgeted spin (hang-proof: convergent barriers, bounded
//  polls, in-bounds LDS — audited).
__global__ __launch_bounds__(512) void k_rnn(
    const float* __restrict__ W_rec,   // [H][H]
    const float* __restrict__ noise,   // [T][B][H]
    float* __restrict__ rnn,           // [T][B][H]: xin+b_rec in, h out
    uint32_t* __restrict__ ex)         // [2][B][H] tagged words
{
    extern __shared__ __align__(16) char smem[];
    unsigned short* Wl  = (unsigned short*)smem;              // 128 KB swizzled
    unsigned short* hbf = (unsigned short*)(smem + 131072);   // 1 KB f16 h
    float*          pr  = (float*)(smem + 132096);            // [8][128] 4 KB

    const int bid = blockIdx.x;
    const int g = bid & 63;        // group == batch
    const int m = bid >> 6;        // member 0..3
    const int tid = threadIdx.x;
    const int w = tid >> 6;        // wave = k-chunk (64 k wide)
    const int l = tid & 63;        // lane -> cols {l, l+64} of slice

    // ---- one-time: W slice -> f16 -> swizzled LDS (thread writes its own
    //      dot slice: cols {l, l+64}, k in [64w, 64w+64)) ----
    {
        const float* p0 = W_rec + (size_t)(m * 128 + l) * NH + w * 64;
        const float* p1 = W_rec + (size_t)(m * 128 + l + 64) * NH + w * 64;
        const int s = (l & 7) << 4;
        char* b0 = (char*)Wl + l * 1024 + w * 128 + s;
        char* b1 = b0 + 65536;                    // (l+64): same s, +64 rows
        #pragma unroll
        for (int j = 0; j < 8; ++j) {
            const float4 qa0 = *(const float4*)(p0 + j * 8);
            const float4 qa1 = *(const float4*)(p0 + j * 8 + 4);
            uint4 ca;
            ca.x = pk2(qa0.x, qa0.y); ca.y = pk2(qa0.z, qa0.w);
            ca.z = pk2(qa1.x, qa1.y); ca.w = pk2(qa1.z, qa1.w);
            *(uint4*)((uintptr_t)b0 ^ (unsigned)(j << 4)) = ca;
            const float4 qb0 = *(const float4*)(p1 + j * 8);
            const float4 qb1 = *(const float4*)(p1 + j * 8 + 4);
            uint4 cb;
            cb.x = pk2(qb0.x, qb0.y); cb.y = pk2(qb0.z, qb0.w);
            cb.z = pk2(qb1.x, qb1.y); cb.w = pk2(qb1.z, qb1.w);
            *(uint4*)((uintptr_t)b1 ^ (unsigned)(j << 4)) = cb;
        }
    }

    const int gc = m * 128 + tid;            // epilogue col (tid<128)

    // poller mapping (tid>=128): one u32 word of one peer
    const int q    = tid - 128;              // 0..383
    const int pp   = q >> 7;                 // 0..2
    const int pm   = pp + (pp >= m ? 1 : 0); // peer member
    const int pcol = pm * 128 + (q & 127);

    // zero f16 h
    hbf[tid] = 0;

    // fp32 h_old carried in registers (epilogue threads only)
    float hreg = 0.f;

    // prefetch t=0 xin(+b_rec)/noise
    float xin_pf = 0.f, noi_pf = 0.f;
    if (tid < 128) {
        xin_pf = rnn[(size_t)g * NH + gc];
        noi_pf = noise[(size_t)g * NH + gc];
    }
    __syncthreads();

    int alive  = 1;
    int budget = 1 << 16;   // launch-global spin budget (hang-proof)

    // dot-phase W base pointers (swizzled)
    const char* wb0 = (const char*)Wl + l * 1024 + w * 128 + ((l & 7) << 4);
    const char* wb1 = wb0 + 65536;

    for (int t = 0; t < T; ++t) {
        // ---- dot: cols {l, l+64}, k in [64w,64w+64), W+h from LDS ----
        float aA0 = 0.f, aA1 = 0.f, aB0 = 0.f, aB1 = 0.f;
        {
            const uint4* hp = (const uint4*)&hbf[w * 64];  // 8 x (8 f16)
            #pragma unroll
            for (int j = 0; j < 8; ++j) {
                const uint4 u = hp[j];                                     // broadcast
                const uint4 A = *(const uint4*)((uintptr_t)wb0 ^ (unsigned)(j << 4));
                const uint4 B = *(const uint4*)((uintptr_t)wb1 ^ (unsigned)(j << 4));
                aA0 = dot2(A.x, u.x, aA0); aA1 = dot2(A.y, u.y, aA1);
                aA0 = dot2(A.z, u.z, aA0); aA1 = dot2(A.w, u.w, aA1);
                aB0 = dot2(B.x, u.x, aB0); aB1 = dot2(B.y, u.y, aB1);
                aB0 = dot2(B.z, u.z, aB0); aB1 = dot2(B.w, u.w, aB1);
            }
        }
        pr[w * 128 + l]      = aA0 + aA1;
        pr[w * 128 + l + 64] = aB0 + aB1;
        __syncthreads();

        const uint32_t want = (uint32_t)(t + 1);
        uint32_t* slot = ex + (size_t)(t & 1) * NB * NH;

        if (tid < 128) {
            // ---- epilogue: reduce 8 chunk-partials, update, publish ----
            float sum = 0.f;
            #pragma unroll
            for (int k = 0; k < 8; ++k) sum += pr[k * 128 + tid];
            const float hn = fmaxf(xin_pf + sum, 0.f);     // b_rec folded in xin
            const float nw = (1.f - ALPHA) * hreg + ALPHA * hn + NSC * noi_pf;
            hreg = nw;
            const uint32_t pk = pack_h(nw, want);
            (void)__hip_atomic_exchange(&slot[(size_t)g * NH + gc], pk,
                                        __ATOMIC_RELAXED, __HIP_MEMORY_SCOPE_AGENT);
            hbf[gc] = (unsigned short)(pk >> 16);          // own col, same rounding
            rnn[((size_t)t * NB + g) * NH + gc] = nw;
            const int tn = (t + 1 < T) ? (t + 1) : t;
            xin_pf = rnn[((size_t)tn * NB + g) * NH + gc];
            noi_pf = noise[((size_t)tn * NB + g) * NH + gc];
        } else {
            // ---- gather: poll one peer word via RMW ----
            uint32_t v;
            if (alive) {
                for (;;) {
                    v = __hip_atomic_fetch_or(&slot[(size_t)g * NH + pcol], 0u,
                                              __ATOMIC_RELAXED, __HIP_MEMORY_SCOPE_AGENT);
                    if ((v & 0xFFFFu) == (want & 0xFFFFu)) break;
                    __builtin_amdgcn_s_sleep(1);
                    if (--budget < 0) { alive = 0; break; }   // fail loudly
                }
            } else {
                v = __hip_atomic_fetch_or(&slot[(size_t)g * NH + pcol], 0u,
                                          __ATOMIC_RELAXED, __HIP_MEMORY_SCOPE_AGENT);
            }
            hbf[pcol] = (unsigned short)(v >> 16);
        }
        __syncthreads();
    }
}

// ---------------------------------------------------------------------------
extern "C" void kernel_launch(void* const* d_in, const int* in_sizes, int n_in,
                              void* d_out, int out_size, void* d_ws, size_t ws_size,
                              hipStream_t stream)
{
    (void)in_sizes; (void)n_in; (void)out_size; (void)ws_size;
    const float* x     = (const float*)d_in[0];
    const float* noise = (const float*)d_in[1];
    const float* W_in  = (const float*)d_in[2];
    const float* W_rec = (const float*)d_in[3];
    const float* b_rec = (const float*)d_in[4];
    const float* W_out = (const float*)d_in[5];
    const float* b_out = (const float*)d_in[6];

    float* out = (float*)d_out;                       // [T*B][O]
    float* rnn = out + (size_t)T * NB * NO;           // [T*B][H] (second output)

    uint32_t* ex = (uint32_t*)d_ws;                   // [2][B][H] = 256 KB

    constexpr int RNN_LDS = 131072 + 1024 + 4096;     // W + hbf + pr = 136192

    // allow >64KB dynamic LDS (idempotent, deterministic, capture-safe)
    (void)hipFuncSetAttribute((const void*)k_rnn,
                              hipFuncAttributeMaxDynamicSharedMemorySize, RNN_LDS);

    // clear exchange tags (replay-deterministic; tag 0 never polled-for)
    hipMemsetAsync(ex, 0, (size_t)2 * NB * NH * sizeof(uint32_t), stream);

    // xin = x @ W_in^T + b_rec  -> written into rnn region (in-place consumed)
    hipLaunchKernelGGL(k_gemm_nt_bias, dim3((T * NB) / 64, NH / 64), dim3(256), 0, stream,
                       x, W_in, b_rec, rnn, T * NB, NH, NI);

    // sequential recurrence: 256 WGs, swizzled-LDS W, fdot2, u32 RMW sync
    hipLaunchKernelGGL(k_rnn, dim3(256), dim3(512), RNN_LDS, stream,
                       W_rec, noise, rnn, ex);

    // output = rnn @ W_out^T + b_out
    hipLaunchKernelGGL(k_gemm_nt_bias, dim3((T * NB) / 64, NO / 64), dim3(256), 0, stream,
                       rnn, W_out, b_out, out, T * NB, NO, NH);
}